// Round 15
// baseline (152.164 us; speedup 1.0000x reference)
//
#include <hip/hip_runtime.h>
#include <hip/hip_bf16.h>

// Problem: B=8, L=1024, DIM=1024, HEADS=12, HEAD_SIZE=64, NOUT=768
// out = einsum('blhd,bmhd->bhlm', rope(head@Wh+bh), rope(tail@Wt+bt)) / 8
// Output (8,12,1024,1024) fp32 = 403 MB.
//
// R15: R14's LDS-staged coalesced stores won (-7.2us) but used __syncthreads
// (= s_waitcnt vmcnt(0) + s_barrier) twice per tile -> 8 full global-store
// drains per block, each exposing store/L2 latency. Replace with raw
// s_barrier + lgkmcnt(0)-only waits (LDS ordering kept; global stores and
// tf prefetch loads stay in flight across barriers).

#define DIM   1024
#define NOUT  768
#define NHEAD 12

typedef __attribute__((ext_vector_type(8))) short bf16x8;
typedef __attribute__((ext_vector_type(4))) float f32x4;

__device__ __forceinline__ ushort f2bf(float f) {
  union { float f; unsigned u; } v; v.f = f;
  unsigned r = v.u + 0x7fffu + ((v.u >> 16) & 1u);   // RNE
  return (ushort)(r >> 16);
}

// async global->LDS, 16B per lane; LDS dest must be lane-linear (m97 pattern)
__device__ __forceinline__ void gload16(const ushort* g, ushort* l) {
  __builtin_amdgcn_global_load_lds(
      (const __attribute__((address_space(1))) unsigned int*)g,
      (__attribute__((address_space(3))) unsigned int*)l, 16, 0, 0);
}

// ---------------------------------------------------------------------------
// prep: [0,4096) convert head/tail fp32->bf16 (16 elem/thread)
//       [4096,4480) W transpose via LDS tile -> bf16 W^T (N-major K-contig)
//       [4480,4608) rope cos/sin table (1024 x 32)
// ---------------------------------------------------------------------------
__global__ __launch_bounds__(256) void prep_kernel(
    const float* __restrict__ head, const float* __restrict__ tail,
    const float* __restrict__ Wh,   const float* __restrict__ Wt_,
    ushort* __restrict__ Hx, ushort* __restrict__ Tx,
    ushort* __restrict__ WtH, ushort* __restrict__ WtT,
    float2* __restrict__ rope)
{
  __shared__ ushort lds[64][72];               // 144B rows, conflict-benign
  const int bx = blockIdx.x, tid = threadIdx.x;

  if (bx < 4096) {                             // X convert: 2 x 8.39M elems
    size_t t = (size_t)bx * 256 + tid;
    const float* src; ushort* dst; size_t e;
    if (t < 524288) { src = head; dst = Hx; e = t * 16; }
    else            { src = tail; dst = Tx; e = (t - 524288) * 16; }
    const float4* p = reinterpret_cast<const float4*>(src + e);
    float4 a = p[0], b = p[1], c = p[2], d = p[3];
    ushort o[16] = { f2bf(a.x), f2bf(a.y), f2bf(a.z), f2bf(a.w),
                     f2bf(b.x), f2bf(b.y), f2bf(b.z), f2bf(b.w),
                     f2bf(c.x), f2bf(c.y), f2bf(c.z), f2bf(c.w),
                     f2bf(d.x), f2bf(d.y), f2bf(d.z), f2bf(d.w) };
    *reinterpret_cast<bf16x8*>(dst + e)     = *reinterpret_cast<bf16x8*>(o);
    *reinterpret_cast<bf16x8*>(dst + e + 8) = *reinterpret_cast<bf16x8*>(o + 8);
  } else if (bx < 4480) {                      // W transpose, 64x64 tiles
    int t2 = bx - 4096;
    int wsel = t2 / 192, tile = t2 % 192;
    int k0 = (tile / 12) * 64, n0 = (tile % 12) * 64;
    const float* W = wsel ? Wt_ : Wh;
    ushort* WT = wsel ? WtT : WtH;
#pragma unroll
    for (int q = 0; q < 16; ++q) {             // coalesced fp32 reads
      int idx = q * 256 + tid;
      int kr = idx >> 6, nc = idx & 63;
      lds[nc][kr] = f2bf(W[(size_t)(k0 + kr) * NOUT + n0 + nc]);
    }
    __syncthreads();
#pragma unroll
    for (int q = 0; q < 2; ++q) {              // coalesced 16B bf16 writes
      int idx = q * 256 + tid;
      int nc = idx >> 3, kg = idx & 7;
      *reinterpret_cast<bf16x8*>(&WT[(size_t)(n0 + nc) * DIM + k0 + kg * 8]) =
          *reinterpret_cast<bf16x8*>(&lds[nc][kg * 8]);
    }
  } else {                                     // rope table
    int j = (bx - 4480) * 256 + tid;           // 0..32767
    int l = j >> 5, i = j & 31;
    float inv = powf(10000.0f, -(float)i / 32.0f);
    float ang = (float)l * inv;
    rope[j] = make_float2(cosf(ang), sinf(ang));
  }
}

// ---------------------------------------------------------------------------
// proj_rope: C(8192x768) = Xbf(8192x1024) @ W^T + bias, RoPE, pack to
// (b, head, l, d) bf16. 128x128 tile, BK=64, 4 waves 2x2, global_load_lds,
// chunk swizzle c^(row&7) (LDS linear). MFMA operands SWAPPED (W first):
// D reg index = output col dd, lane r = output row l.
// ---------------------------------------------------------------------------
__global__ __launch_bounds__(256) void proj_rope_kernel(
    const ushort* __restrict__ Hx,  const ushort* __restrict__ Tx,
    const ushort* __restrict__ WtH, const ushort* __restrict__ WtT,
    const float*  __restrict__ bh,  const float*  __restrict__ bt,
    const float2* __restrict__ rope,
    ushort* __restrict__ Hb, ushort* __restrict__ Tb)
{
  const bool sel = (blockIdx.z != 0);
  const ushort* X    = sel ? Tx  : Hx;
  const ushort* Wt   = sel ? WtT : WtH;
  const float*  bias = sel ? bt  : bh;
  ushort*       Out  = sel ? Tb  : Hb;

  __shared__ ushort As[128 * 64];              // linear; logical row*64+col
  __shared__ ushort Bs[128 * 64];

  const int tid = threadIdx.x;
  const int m0 = blockIdx.x * 128;             // into 8192 = b*1024+l
  const int n0 = blockIdx.y * 128;             // into 768  = head*64+d
  const int wid = tid >> 6, lane = tid & 63;
  const int wm = wid >> 1, wn = wid & 1;       // 2x2 waves, 64x64 each
  const int r = lane & 15, g = lane >> 4;
  const int r7 = r & 7;

  f32x4 acc[4][4] = {};                        // [n][m]

  for (int k0 = 0; k0 < DIM; k0 += 64) {
#pragma unroll
    for (int i = 0; i < 4; ++i) {              // A: 128 rows x 8 chunks(16B)
      int task = i * 256 + tid;
      int row = task >> 3, c = task & 7;
      int csrc = c ^ (row & 7);                // pre-swizzled source chunk
      gload16(X + (size_t)(m0 + row) * DIM + k0 + csrc * 8, &As[task * 8]);
    }
#pragma unroll
    for (int i = 0; i < 4; ++i) {              // B: 128 rows x 8 chunks
      int task = i * 256 + tid;
      int row = task >> 3, c = task & 7;
      int csrc = c ^ (row & 7);
      gload16(Wt + (size_t)(n0 + row) * DIM + k0 + csrc * 8, &Bs[task * 8]);
    }
    __syncthreads();

    bf16x8 af[2][4], bfv[2][4];
#pragma unroll
    for (int ks = 0; ks < 2; ++ks) {
      int cs = (ks * 4 + g) ^ r7;              // swizzled read chunk
#pragma unroll
      for (int m = 0; m < 4; ++m)
        af[ks][m] = *reinterpret_cast<const bf16x8*>(
            &As[(wm * 64 + m * 16 + r) * 64 + cs * 8]);
#pragma unroll
      for (int n = 0; n < 4; ++n)
        bfv[ks][n] = *reinterpret_cast<const bf16x8*>(
            &Bs[(wn * 64 + n * 16 + r) * 64 + cs * 8]);
    }
#pragma unroll
    for (int n = 0; n < 4; ++n)
#pragma unroll
      for (int m = 0; m < 4; ++m) {
        acc[n][m] = __builtin_amdgcn_mfma_f32_16x16x32_bf16(
            bfv[0][n], af[0][m], acc[n][m], 0, 0, 0);
        acc[n][m] = __builtin_amdgcn_mfma_f32_16x16x32_bf16(
            bfv[1][n], af[1][m], acc[n][m], 0, 0, 0);
      }
    __syncthreads();
  }

  // Epilogue: bias + RoPE + pack. Thread holds 4 consecutive dd (g*4+j)
  // for each (n,m); rope pair dd^1 is the adjacent register.
#pragma unroll
  for (int n = 0; n < 4; ++n) {
    int col = n0 + wn * 64 + n * 16 + g * 4;   // 4-aligned, head-contained
    int hd = col >> 6, dd = col & 63;
    int ii = dd >> 1;                          // even; pairs (ii, ii+1)
    float4 bs4 = *reinterpret_cast<const float4*>(&bias[col]);
#pragma unroll
    for (int m = 0; m < 4; ++m) {
      int grow = m0 + wm * 64 + m * 16 + r;
      int l = grow & 1023, b = grow >> 10;
      float4 rp = *reinterpret_cast<const float4*>(&rope[l * 32 + ii]);
      float v0 = acc[n][m][0] + bs4.x;
      float v1 = acc[n][m][1] + bs4.y;
      float v2 = acc[n][m][2] + bs4.z;
      float v3 = acc[n][m][3] + bs4.w;
      ushort o[4] = { f2bf(v0 * rp.x - v1 * rp.y),
                      f2bf(v1 * rp.x + v0 * rp.y),
                      f2bf(v2 * rp.z - v3 * rp.w),
                      f2bf(v3 * rp.z + v2 * rp.w) };
      *reinterpret_cast<ushort4*>(
          &Out[(((size_t)b * NHEAD + hd) * 1024 + l) * 64 + dd]) =
          *reinterpret_cast<ushort4*>(o);
    }
  }
}

// ---------------------------------------------------------------------------
// logits: per (b,h): C[l][m] = sum_d H[l][d] T[m][d] * 0.125
// R14 structure (4 m-tiles/block, hf once, tf 2-deep, LDS-staged coalesced
// stores) with lgkm-only raw barriers: global stores + tf loads never
// drained in-loop. Grid 1536, XCD-pinned (slice z on XCD z%8).
// ---------------------------------------------------------------------------
__global__ __launch_bounds__(256) void logits_kernel(
    const ushort* __restrict__ Hb, const ushort* __restrict__ Tb,
    float* __restrict__ out)
{
  __shared__ float cs[128 * 128];              // 64KB store-staging tile
  const int f = blockIdx.x;                    // 0..1535
  const int rx = f & 7, q = f >> 3;            // rx = XCD residue
  const int zq = q >> 4, jj = q & 15;          // zq 0..11, jj 0..15
  const int z = zq * 8 + rx;                   // slice 0..95
  const int l0 = (jj >> 1) * 128;              // 8 row-groups
  const int mq = (jj & 1) * 512;               // 2 col-quads of 4x128

  const int tid = threadIdx.x;
  const int wid = tid >> 6, lane = tid & 63;
  const int wl = wid >> 1, wm = wid & 1;       // 2(l) x 2(m) waves
  const int r = lane & 15, g = lane >> 4;
  const size_t zo = (size_t)z << 16;           // *1024*64
  const ushort* Hrow = Hb + zo + (size_t)(l0 + wl * 64 + r) * 64 + g * 8;
  const ushort* Trow = Tb + zo + (size_t)(mq + wm * 64 + r) * 64 + g * 8;
  float* C = out + ((size_t)z << 20);

  bf16x8 hf[4][2];                             // H fragments, loaded once
#pragma unroll
  for (int i = 0; i < 4; ++i)
#pragma unroll
    for (int ks = 0; ks < 2; ++ks)
      hf[i][ks] = *reinterpret_cast<const bf16x8*>(Hrow + i * 1024 + ks * 32);

// lgkm-only barrier: LDS ordering without draining global stores/loads
#define LBAR()                                                                \
  do {                                                                        \
    asm volatile("s_waitcnt lgkmcnt(0)" ::: "memory");                        \
    __builtin_amdgcn_s_barrier();                                             \
    __builtin_amdgcn_sched_barrier(0);                                        \
  } while (0)

#define LOADTF(dst, t)                                                        \
  _Pragma("unroll") for (int i = 0; i < 4; ++i)                               \
  _Pragma("unroll") for (int ks = 0; ks < 2; ++ks)                            \
      dst[i][ks] = *reinterpret_cast<const bf16x8*>(                          \
          Trow + (t) * 8192 + i * 1024 + ks * 32);

#define TILE(tfv, t)                                                          \
  do {                                                                        \
    f32x4 acc[4][4] = {};                                                     \
    _Pragma("unroll") for (int mt = 0; mt < 4; ++mt)                          \
    _Pragma("unroll") for (int lt = 0; lt < 4; ++lt) {                        \
      acc[mt][lt] = __builtin_amdgcn_mfma_f32_16x16x32_bf16(                  \
          tfv[mt][0], hf[lt][0], acc[mt][lt], 0, 0, 0);                       \
      acc[mt][lt] = __builtin_amdgcn_mfma_f32_16x16x32_bf16(                  \
          tfv[mt][1], hf[lt][1], acc[mt][lt], 0, 0, 0);                       \
    }                                                                         \
    /* acc*scale -> LDS, chunk-XOR swizzled */                                \
    _Pragma("unroll") for (int lt = 0; lt < 4; ++lt)                          \
    _Pragma("unroll") for (int mt = 0; mt < 4; ++mt) {                        \
      int row = wl * 64 + lt * 16 + r;                                        \
      int ch  = wm * 16 + mt * 4 + g;          /* m-chunk 0..31 */            \
      int chs = ch ^ (row & 7);                                               \
      *reinterpret_cast<f32x4*>(&cs[row * 128 + chs * 4]) =                   \
          acc[mt][lt] * 0.125f;                                               \
    }                                                                         \
    LBAR();                                    /* writes visible to readers */\
    /* coalesced store: 2 full 512B rows per instruction */                   \
    _Pragma("unroll") for (int k = 0; k < 16; ++k) {                          \
      int row = wid * 32 + k * 2 + (lane >> 5);                               \
      int ch  = lane & 31;                                                    \
      int chs = ch ^ (row & 7);                                               \
      f32x4 v = *reinterpret_cast<const f32x4*>(&cs[row * 128 + chs * 4]);    \
      *reinterpret_cast<f32x4*>(                                              \
          &C[(size_t)(l0 + row) * 1024 + mq + (t) * 128 + ch * 4]) = v;       \
    }                                                                         \
    LBAR();                                    /* reads done before rewrite */\
  } while (0)

  bf16x8 tfA[4][2], tfB[4][2];
  LOADTF(tfA, 0);
  LOADTF(tfB, 1);
  TILE(tfA, 0);
  LOADTF(tfA, 2);
  TILE(tfB, 1);
  LOADTF(tfB, 3);
  TILE(tfA, 2);
  TILE(tfB, 3);
#undef LOADTF
#undef TILE
#undef LBAR
}

// ---------------------------------------------------------------------------
extern "C" void kernel_launch(void* const* d_in, const int* in_sizes, int n_in,
                              void* d_out, int out_size, void* d_ws, size_t ws_size,
                              hipStream_t stream)
{
  const float* head   = (const float*)d_in[0];
  const float* tail   = (const float*)d_in[1];
  const float* W_head = (const float*)d_in[2];
  const float* b_head = (const float*)d_in[3];
  const float* W_tail = (const float*)d_in[4];
  const float* b_tail = (const float*)d_in[5];
  float* out = (float*)d_out;

  char* ws = (char*)d_ws;
  ushort* WtH  = (ushort*)(ws);                    // 768*1024*2     = 1572864
  ushort* WtT  = (ushort*)(ws + 1572864);          // 1572864
  float2* rope = (float2*)(ws + 3145728);          // 1024*32*8      = 262144
  ushort* Hb   = (ushort*)(ws + 3407872);          // 8*12*1024*64*2 = 12582912
  ushort* Tb   = (ushort*)(ws + 15990784);         // 12582912 (~28.6MB ws)

  // bf16 copies of head/tail live in d_out's first 33.5MB: consumed by
  // proj_rope, then overwritten by logits (stream-ordered, deterministic).
  ushort* Hx = (ushort*)d_out;                     // 8192*1024*2 = 16777216
  ushort* Tx = Hx + 8388608;

  prep_kernel<<<dim3(4608), dim3(256), 0, stream>>>(
      head, tail, W_head, W_tail, Hx, Tx, WtH, WtT, rope);
  proj_rope_kernel<<<dim3(64, 6, 2), dim3(256), 0, stream>>>(
      Hx, Tx, WtH, WtT, b_head, b_tail, rope, Hb, Tb);
  logits_kernel<<<dim3(1536), dim3(256), 0, stream>>>(Hb, Tb, out);
}

// Round 16
// 149.906 us; speedup vs baseline: 1.0151x; 1.0151x over previous
//
#include <hip/hip_runtime.h>
#include <hip/hip_bf16.h>

// Problem: B=8, L=1024, DIM=1024, HEADS=12, HEAD_SIZE=64, NOUT=768
// out = einsum('blhd,bmhd->bhlm', rope(head@Wh+bh), rope(tail@Wt+bt)) / 8
// Output (8,12,1024,1024) fp32 = 403 MB.
//
// R16: R15 (lgkm-only barriers) was noise/slight regression -> revert to
// __syncthreads (R14). New single variable: logits store-staging LDS halved
// to 32KB (cs[64][128]) via two 64-row stage/store phases per tile ->
// 3-4 blocks/CU instead of 2 (store-BW needs in-flight writes; fill's
// 6.9TB/s runs at much higher wave count). 4 barriers/tile (drains proven
// ~free by R14/R15 A/B).

#define DIM   1024
#define NOUT  768
#define NHEAD 12

typedef __attribute__((ext_vector_type(8))) short bf16x8;
typedef __attribute__((ext_vector_type(4))) float f32x4;

__device__ __forceinline__ ushort f2bf(float f) {
  union { float f; unsigned u; } v; v.f = f;
  unsigned r = v.u + 0x7fffu + ((v.u >> 16) & 1u);   // RNE
  return (ushort)(r >> 16);
}

// async global->LDS, 16B per lane; LDS dest must be lane-linear (m97 pattern)
__device__ __forceinline__ void gload16(const ushort* g, ushort* l) {
  __builtin_amdgcn_global_load_lds(
      (const __attribute__((address_space(1))) unsigned int*)g,
      (__attribute__((address_space(3))) unsigned int*)l, 16, 0, 0);
}

// ---------------------------------------------------------------------------
// prep: [0,4096) convert head/tail fp32->bf16 (16 elem/thread)
//       [4096,4480) W transpose via LDS tile -> bf16 W^T (N-major K-contig)
//       [4480,4608) rope cos/sin table (1024 x 32)
// ---------------------------------------------------------------------------
__global__ __launch_bounds__(256) void prep_kernel(
    const float* __restrict__ head, const float* __restrict__ tail,
    const float* __restrict__ Wh,   const float* __restrict__ Wt_,
    ushort* __restrict__ Hx, ushort* __restrict__ Tx,
    ushort* __restrict__ WtH, ushort* __restrict__ WtT,
    float2* __restrict__ rope)
{
  __shared__ ushort lds[64][72];               // 144B rows, conflict-benign
  const int bx = blockIdx.x, tid = threadIdx.x;

  if (bx < 4096) {                             // X convert: 2 x 8.39M elems
    size_t t = (size_t)bx * 256 + tid;
    const float* src; ushort* dst; size_t e;
    if (t < 524288) { src = head; dst = Hx; e = t * 16; }
    else            { src = tail; dst = Tx; e = (t - 524288) * 16; }
    const float4* p = reinterpret_cast<const float4*>(src + e);
    float4 a = p[0], b = p[1], c = p[2], d = p[3];
    ushort o[16] = { f2bf(a.x), f2bf(a.y), f2bf(a.z), f2bf(a.w),
                     f2bf(b.x), f2bf(b.y), f2bf(b.z), f2bf(b.w),
                     f2bf(c.x), f2bf(c.y), f2bf(c.z), f2bf(c.w),
                     f2bf(d.x), f2bf(d.y), f2bf(d.z), f2bf(d.w) };
    *reinterpret_cast<bf16x8*>(dst + e)     = *reinterpret_cast<bf16x8*>(o);
    *reinterpret_cast<bf16x8*>(dst + e + 8) = *reinterpret_cast<bf16x8*>(o + 8);
  } else if (bx < 4480) {                      // W transpose, 64x64 tiles
    int t2 = bx - 4096;
    int wsel = t2 / 192, tile = t2 % 192;
    int k0 = (tile / 12) * 64, n0 = (tile % 12) * 64;
    const float* W = wsel ? Wt_ : Wh;
    ushort* WT = wsel ? WtT : WtH;
#pragma unroll
    for (int q = 0; q < 16; ++q) {             // coalesced fp32 reads
      int idx = q * 256 + tid;
      int kr = idx >> 6, nc = idx & 63;
      lds[nc][kr] = f2bf(W[(size_t)(k0 + kr) * NOUT + n0 + nc]);
    }
    __syncthreads();
#pragma unroll
    for (int q = 0; q < 2; ++q) {              // coalesced 16B bf16 writes
      int idx = q * 256 + tid;
      int nc = idx >> 3, kg = idx & 7;
      *reinterpret_cast<bf16x8*>(&WT[(size_t)(n0 + nc) * DIM + k0 + kg * 8]) =
          *reinterpret_cast<bf16x8*>(&lds[nc][kg * 8]);
    }
  } else {                                     // rope table
    int j = (bx - 4480) * 256 + tid;           // 0..32767
    int l = j >> 5, i = j & 31;
    float inv = powf(10000.0f, -(float)i / 32.0f);
    float ang = (float)l * inv;
    rope[j] = make_float2(cosf(ang), sinf(ang));
  }
}

// ---------------------------------------------------------------------------
// proj_rope: C(8192x768) = Xbf(8192x1024) @ W^T + bias, RoPE, pack to
// (b, head, l, d) bf16. 128x128 tile, BK=64, 4 waves 2x2, global_load_lds,
// chunk swizzle c^(row&7) (LDS linear). MFMA operands SWAPPED (W first):
// D reg index = output col dd, lane r = output row l.
// ---------------------------------------------------------------------------
__global__ __launch_bounds__(256) void proj_rope_kernel(
    const ushort* __restrict__ Hx,  const ushort* __restrict__ Tx,
    const ushort* __restrict__ WtH, const ushort* __restrict__ WtT,
    const float*  __restrict__ bh,  const float*  __restrict__ bt,
    const float2* __restrict__ rope,
    ushort* __restrict__ Hb, ushort* __restrict__ Tb)
{
  const bool sel = (blockIdx.z != 0);
  const ushort* X    = sel ? Tx  : Hx;
  const ushort* Wt   = sel ? WtT : WtH;
  const float*  bias = sel ? bt  : bh;
  ushort*       Out  = sel ? Tb  : Hb;

  __shared__ ushort As[128 * 64];              // linear; logical row*64+col
  __shared__ ushort Bs[128 * 64];

  const int tid = threadIdx.x;
  const int m0 = blockIdx.x * 128;             // into 8192 = b*1024+l
  const int n0 = blockIdx.y * 128;             // into 768  = head*64+d
  const int wid = tid >> 6, lane = tid & 63;
  const int wm = wid >> 1, wn = wid & 1;       // 2x2 waves, 64x64 each
  const int r = lane & 15, g = lane >> 4;
  const int r7 = r & 7;

  f32x4 acc[4][4] = {};                        // [n][m]

  for (int k0 = 0; k0 < DIM; k0 += 64) {
#pragma unroll
    for (int i = 0; i < 4; ++i) {              // A: 128 rows x 8 chunks(16B)
      int task = i * 256 + tid;
      int row = task >> 3, c = task & 7;
      int csrc = c ^ (row & 7);                // pre-swizzled source chunk
      gload16(X + (size_t)(m0 + row) * DIM + k0 + csrc * 8, &As[task * 8]);
    }
#pragma unroll
    for (int i = 0; i < 4; ++i) {              // B: 128 rows x 8 chunks
      int task = i * 256 + tid;
      int row = task >> 3, c = task & 7;
      int csrc = c ^ (row & 7);
      gload16(Wt + (size_t)(n0 + row) * DIM + k0 + csrc * 8, &Bs[task * 8]);
    }
    __syncthreads();

    bf16x8 af[2][4], bfv[2][4];
#pragma unroll
    for (int ks = 0; ks < 2; ++ks) {
      int cs2 = (ks * 4 + g) ^ r7;             // swizzled read chunk
#pragma unroll
      for (int m = 0; m < 4; ++m)
        af[ks][m] = *reinterpret_cast<const bf16x8*>(
            &As[(wm * 64 + m * 16 + r) * 64 + cs2 * 8]);
#pragma unroll
      for (int n = 0; n < 4; ++n)
        bfv[ks][n] = *reinterpret_cast<const bf16x8*>(
            &Bs[(wn * 64 + n * 16 + r) * 64 + cs2 * 8]);
    }
#pragma unroll
    for (int n = 0; n < 4; ++n)
#pragma unroll
      for (int m = 0; m < 4; ++m) {
        acc[n][m] = __builtin_amdgcn_mfma_f32_16x16x32_bf16(
            bfv[0][n], af[0][m], acc[n][m], 0, 0, 0);
        acc[n][m] = __builtin_amdgcn_mfma_f32_16x16x32_bf16(
            bfv[1][n], af[1][m], acc[n][m], 0, 0, 0);
      }
    __syncthreads();
  }

  // Epilogue: bias + RoPE + pack. Thread holds 4 consecutive dd (g*4+j)
  // for each (n,m); rope pair dd^1 is the adjacent register.
#pragma unroll
  for (int n = 0; n < 4; ++n) {
    int col = n0 + wn * 64 + n * 16 + g * 4;   // 4-aligned, head-contained
    int hd = col >> 6, dd = col & 63;
    int ii = dd >> 1;                          // even; pairs (ii, ii+1)
    float4 bs4 = *reinterpret_cast<const float4*>(&bias[col]);
#pragma unroll
    for (int m = 0; m < 4; ++m) {
      int grow = m0 + wm * 64 + m * 16 + r;
      int l = grow & 1023, b = grow >> 10;
      float4 rp = *reinterpret_cast<const float4*>(&rope[l * 32 + ii]);
      float v0 = acc[n][m][0] + bs4.x;
      float v1 = acc[n][m][1] + bs4.y;
      float v2 = acc[n][m][2] + bs4.z;
      float v3 = acc[n][m][3] + bs4.w;
      ushort o[4] = { f2bf(v0 * rp.x - v1 * rp.y),
                      f2bf(v1 * rp.x + v0 * rp.y),
                      f2bf(v2 * rp.z - v3 * rp.w),
                      f2bf(v3 * rp.z + v2 * rp.w) };
      *reinterpret_cast<ushort4*>(
          &Out[(((size_t)b * NHEAD + hd) * 1024 + l) * 64 + dd]) =
          *reinterpret_cast<ushort4*>(o);
    }
  }
}

// ---------------------------------------------------------------------------
// logits: per (b,h): C[l][m] = sum_d H[l][d] T[m][d] * 0.125
// R14 structure (4 m-tiles/block, hf once, tf 2-deep static pipeline, LDS-
// staged coalesced stores) with 32KB staging: each tile stages/stores in
// two 64-row halves (wl=0 rows 0-63, wl=1 rows 64-127) -> 3-4 blocks/CU.
// Grid 1536, XCD-pinned (slice z on XCD z%8).
// ---------------------------------------------------------------------------
__global__ __launch_bounds__(256) void logits_kernel(
    const ushort* __restrict__ Hb, const ushort* __restrict__ Tb,
    float* __restrict__ out)
{
  __shared__ float cs[64 * 128];               // 32KB store-staging tile
  const int f = blockIdx.x;                    // 0..1535
  const int rx = f & 7, q = f >> 3;            // rx = XCD residue
  const int zq = q >> 4, jj = q & 15;          // zq 0..11, jj 0..15
  const int z = zq * 8 + rx;                   // slice 0..95
  const int l0 = (jj >> 1) * 128;              // 8 row-groups
  const int mq = (jj & 1) * 512;               // 2 col-quads of 4x128

  const int tid = threadIdx.x;
  const int wid = tid >> 6, lane = tid & 63;
  const int wl = wid >> 1, wm = wid & 1;       // 2(l) x 2(m) waves
  const int r = lane & 15, g = lane >> 4;
  const size_t zo = (size_t)z << 16;           // *1024*64
  const ushort* Hrow = Hb + zo + (size_t)(l0 + wl * 64 + r) * 64 + g * 8;
  const ushort* Trow = Tb + zo + (size_t)(mq + wm * 64 + r) * 64 + g * 8;
  float* C = out + ((size_t)z << 20);

  bf16x8 hf[4][2];                             // H fragments, loaded once
#pragma unroll
  for (int i = 0; i < 4; ++i)
#pragma unroll
    for (int ks = 0; ks < 2; ++ks)
      hf[i][ks] = *reinterpret_cast<const bf16x8*>(Hrow + i * 1024 + ks * 32);

#define LOADTF(dst, t)                                                        \
  _Pragma("unroll") for (int i = 0; i < 4; ++i)                               \
  _Pragma("unroll") for (int ks = 0; ks < 2; ++ks)                            \
      dst[i][ks] = *reinterpret_cast<const bf16x8*>(                          \
          Trow + (t) * 8192 + i * 1024 + ks * 32);

// stage one 64-row half (only waves with wl==half execute the writes)
#define STAGE_HALF(half)                                                      \
  do {                                                                        \
    if (wl == (half)) {                                                       \
      _Pragma("unroll") for (int lt = 0; lt < 4; ++lt)                        \
      _Pragma("unroll") for (int mt = 0; mt < 4; ++mt) {                      \
        int row = lt * 16 + r;                 /* 0..63 local */              \
        int ch  = wm * 16 + mt * 4 + g;        /* m-chunk 0..31 */            \
        int chs = ch ^ (row & 7);                                             \
        *reinterpret_cast<f32x4*>(&cs[row * 128 + chs * 4]) =                 \
            acc[mt][lt] * 0.125f;                                             \
      }                                                                       \
    }                                                                         \
  } while (0)

// store one 64-row half: 2 full 512B rows per instruction, 8 insts/thread
#define STORE_HALF(t, base)                                                   \
  do {                                                                        \
    _Pragma("unroll") for (int k = 0; k < 8; ++k) {                           \
      int row = wid * 16 + k * 2 + (lane >> 5);                               \
      int ch  = lane & 31;                                                    \
      int chs = ch ^ (row & 7);                                               \
      f32x4 v = *reinterpret_cast<const f32x4*>(&cs[row * 128 + chs * 4]);    \
      *reinterpret_cast<f32x4*>(                                              \
          &C[(size_t)(l0 + (base) + row) * 1024 + mq + (t) * 128 + ch * 4])   \
          = v;                                                                \
    }                                                                         \
  } while (0)

#define TILE(tfv, t)                                                          \
  do {                                                                        \
    f32x4 acc[4][4] = {};                                                     \
    _Pragma("unroll") for (int mt = 0; mt < 4; ++mt)                          \
    _Pragma("unroll") for (int lt = 0; lt < 4; ++lt) {                        \
      acc[mt][lt] = __builtin_amdgcn_mfma_f32_16x16x32_bf16(                  \
          tfv[mt][0], hf[lt][0], acc[mt][lt], 0, 0, 0);                       \
      acc[mt][lt] = __builtin_amdgcn_mfma_f32_16x16x32_bf16(                  \
          tfv[mt][1], hf[lt][1], acc[mt][lt], 0, 0, 0);                       \
    }                                                                         \
    STAGE_HALF(0);                                                            \
    __syncthreads();                                                          \
    STORE_HALF(t, 0);                                                         \
    __syncthreads();                                                          \
    STAGE_HALF(1);                                                            \
    __syncthreads();                                                          \
    STORE_HALF(t, 64);                                                        \
    __syncthreads();                                                          \
  } while (0)

  bf16x8 tfA[4][2], tfB[4][2];
  LOADTF(tfA, 0);
  LOADTF(tfB, 1);
  TILE(tfA, 0);
  LOADTF(tfA, 2);
  TILE(tfB, 1);
  LOADTF(tfB, 3);
  TILE(tfA, 2);
  TILE(tfB, 3);
#undef LOADTF
#undef STAGE_HALF
#undef STORE_HALF
#undef TILE
}

// ---------------------------------------------------------------------------
extern "C" void kernel_launch(void* const* d_in, const int* in_sizes, int n_in,
                              void* d_out, int out_size, void* d_ws, size_t ws_size,
                              hipStream_t stream)
{
  const float* head   = (const float*)d_in[0];
  const float* tail   = (const float*)d_in[1];
  const float* W_head = (const float*)d_in[2];
  const float* b_head = (const float*)d_in[3];
  const float* W_tail = (const float*)d_in[4];
  const float* b_tail = (const float*)d_in[5];
  float* out = (float*)d_out;

  char* ws = (char*)d_ws;
  ushort* WtH  = (ushort*)(ws);                    // 768*1024*2     = 1572864
  ushort* WtT  = (ushort*)(ws + 1572864);          // 1572864
  float2* rope = (float2*)(ws + 3145728);          // 1024*32*8      = 262144
  ushort* Hb   = (ushort*)(ws + 3407872);          // 8*12*1024*64*2 = 12582912
  ushort* Tb   = (ushort*)(ws + 15990784);         // 12582912 (~28.6MB ws)

  // bf16 copies of head/tail live in d_out's first 33.5MB: consumed by
  // proj_rope, then overwritten by logits (stream-ordered, deterministic).
  ushort* Hx = (ushort*)d_out;                     // 8192*1024*2 = 16777216
  ushort* Tx = Hx + 8388608;

  prep_kernel<<<dim3(4608), dim3(256), 0, stream>>>(
      head, tail, W_head, W_tail, Hx, Tx, WtH, WtT, rope);
  proj_rope_kernel<<<dim3(64, 6, 2), dim3(256), 0, stream>>>(
      Hx, Tx, WtH, WtT, b_head, b_tail, rope, Hb, Tb);
  logits_kernel<<<dim3(1536), dim3(256), 0, stream>>>(Hb, Tb, out);
}